// Round 4
// baseline (352.956 us; speedup 1.0000x reference)
//
#include <hip/hip_runtime.h>

typedef unsigned short u16;
typedef unsigned int u32;
typedef __attribute__((ext_vector_type(8))) short short8;
typedef __attribute__((ext_vector_type(4))) float f32x4;

__device__ __forceinline__ u16 f2b(float f) {
  union { float f; u32 i; } v; v.f = f;
  u32 i = v.i;
  return (u16)((i + 0x7FFFu + ((i >> 16) & 1u)) >> 16);
}
__device__ __forceinline__ float lo16(u32 x) { union { u32 i; float f; } v; v.i = x << 16; return v.f; }
__device__ __forceinline__ float hi16(u32 x) { union { u32 i; float f; } v; v.i = x & 0xffff0000u; return v.f; }
__device__ __forceinline__ u32 pack2(float a, float b) { return (u32)f2b(a) | ((u32)f2b(b) << 16); }

// Sizes: N=2, M=512, D_IN=64, D=128, H=8. Rows = N*M = 1024. hn = h*2+n in [0,16).
__device__ __align__(16) float g_h[1024 * 128];
__device__ __align__(16) u16   g_hb[1024 * 128];
__device__ __align__(16) u16   g_Wt[24 * 128 * 128];   // W^T per (proj,head): [ph][e][d] bf16
__device__ __align__(16) u16   g_w1t[128 * 1024];      // fv_w1^T: [e][k] bf16
__device__ __align__(16) u16   g_w2t[128 * 128];       // fv_w2^T: [e][k] bf16
__device__ __align__(16) u16   g_fat[2 * 128 * 128];   // fe_w1^T halves: [half][e][k] bf16
__device__ __align__(16) u16   g_K[16 * 512 * 128];
__device__ __align__(16) u16   g_Q[16 * 512 * 128];
__device__ __align__(16) u16   g_V[16 * 512 * 128];
__device__ __align__(16) u16   g_Opb[512 * 64 * 128];  // bf16 flash partials
__device__ __align__(16) float g_ml[512 * 64 * 2];
__device__ __align__(16) float g_A[1024 * 128];
__device__ __align__(16) float g_Bm[1024 * 128];

// Monotonic barrier counters (never reset; generation = ticket/512).
__device__ u32 g_c1, g_c2, g_c3;

// Hand-rolled all-block barrier for a 512-block grid. Every block arrives
// exactly once per launch (producers after their work, non-producers
// immediately), so the barrier opens exactly when the slowest producer
// arrives. Monotonic counter + ticket-derived generation -> no reset needed
// across graph replays. Release: per-block __threadfence (L2 writeback on
// that XCD). Acquire: __threadfence after the spin (L2 invalidate) so
// cross-XCD reads see fresh data.
__device__ __forceinline__ void gbar(u32* ctr, u32& gen, bool have_gen) {
  __syncthreads();                  // all block stores complete (vmcnt drained)
  if (threadIdx.x == 0) {
    __threadfence();                // device-scope release
    u32 t = __hip_atomic_fetch_add(ctr, 1u, __ATOMIC_RELAXED,
                                   __HIP_MEMORY_SCOPE_AGENT);
    if (!have_gen) gen = t >> 9;    // /512: same value for all blocks of a launch
    u32 target = (gen + 1u) << 9;
    while (__hip_atomic_load(ctr, __ATOMIC_RELAXED, __HIP_MEMORY_SCOPE_AGENT) <
           target)
      __builtin_amdgcn_s_sleep(8);
  }
  __syncthreads();
  __threadfence();                  // device-scope acquire before consuming
}

// Per-phase shared structs; per-kernel unions.
struct SM1 { float xr[128]; float hids[512]; float red[2048]; };
struct SM2 { u16 hs[64 * 136]; u16 Wt[128 * 136]; };
struct SM3 { u16 Ks[64 * 136]; u16 Qs[64 * 136]; u16 Vt[128 * 72];
             u16 Pw[4 * 16 * 72]; float alphas[64]; };
struct SMfv { u16 atts[16 * 1032]; u16 hidb[16 * 136]; u16 x2b[16 * 136]; };
struct SM6 { float As[512]; float w2s[128]; };
union __align__(16) SMA { SM1 p1; SM2 p2; SM3 p3; };    // 62720 B -> 2 blk/CU
union __align__(16) SMB { SMfv pf; SM6 p6; };           // 41728 B -> 2 blk/CU

// ---------------- Phase 1: f_node (+ weight pre-transpose piggyback) ------------
__device__ __forceinline__ void phase_fnode(SM1& sm, int b, int tx,
    const float* __restrict__ x, const float* __restrict__ w1,
    const float* __restrict__ b1, const float* __restrict__ w2,
    const float* __restrict__ b2, const float* __restrict__ wk,
    const float* __restrict__ wq, const float* __restrict__ wv,
    const float* __restrict__ fvw1, const float* __restrict__ fvw2,
    const float* __restrict__ few1) {
  int row0 = b * 2;
  if (tx < 128) {
    int r = tx >> 6, k = tx & 63;
    sm.xr[tx] = x[(row0 + r) * 64 + k] + sinf((float)k * (5.0f / 63.0f));
  }
  {
    int base = b * 1280 + tx;
#pragma unroll
    for (int t = 0; t < 5; t++) {
      int idx = base + t * 256;
      if (idx < 393216) {
        int ph = idx >> 14, rem = idx & 16383, e = rem >> 7, d = rem & 127;
        int proj = ph >> 3, head = ph & 7;
        const float* W = (proj == 0) ? wk : (proj == 1) ? wq : wv;
        g_Wt[idx] = f2b(W[head * 16384 + d * 128 + e]);
      } else if (idx < 524288) {
        int idx2 = idx - 393216;          // fv_w1^T
        int e = idx2 >> 10, k = idx2 & 1023;
        g_w1t[idx2] = f2b(fvw1[k * 128 + e]);
      } else if (idx < 540672) {
        int idx3 = idx - 524288;          // fv_w2^T
        int e = idx3 >> 7, k = idx3 & 127;
        g_w2t[idx3] = f2b(fvw2[k * 128 + e]);
      } else if (idx < 573440) {
        int idx4 = idx - 540672;          // fe_w1^T halves
        int half = idx4 >> 14, rem = idx4 & 16383;
        int e = rem >> 7, k = rem & 127;
        g_fat[idx4] = f2b(few1[(half * 128 + k) * 128 + e]);
      }
    }
  }
  __syncthreads();
  {
    int ks = tx >> 6, cg = tx & 63;
    float acc[2][4] = {};
#pragma unroll 4
    for (int i = 0; i < 16; i++) {
      int k = ks * 16 + i;
      float4 w4 = *(const float4*)&w1[k * 256 + cg * 4];
      float a0 = sm.xr[k], a1 = sm.xr[64 + k];
      acc[0][0] = fmaf(a0, w4.x, acc[0][0]); acc[0][1] = fmaf(a0, w4.y, acc[0][1]);
      acc[0][2] = fmaf(a0, w4.z, acc[0][2]); acc[0][3] = fmaf(a0, w4.w, acc[0][3]);
      acc[1][0] = fmaf(a1, w4.x, acc[1][0]); acc[1][1] = fmaf(a1, w4.y, acc[1][1]);
      acc[1][2] = fmaf(a1, w4.z, acc[1][2]); acc[1][3] = fmaf(a1, w4.w, acc[1][3]);
    }
#pragma unroll
    for (int r = 0; r < 2; r++)
      *(float4*)&sm.red[ks * 512 + r * 256 + cg * 4] = *(float4*)acc[r];
  }
  __syncthreads();
#pragma unroll
  for (int jo = 0; jo < 2; jo++) {
    int o = jo * 256 + tx;
    float s = sm.red[o] + sm.red[512 + o] + sm.red[1024 + o] + sm.red[1536 + o];
    sm.hids[o] = fmaxf(s + b1[o & 255], 0.0f);
  }
  __syncthreads();
  {
    int ks = tx >> 5, eg = tx & 31;
    float acc[2][4] = {};
#pragma unroll 4
    for (int i = 0; i < 32; i++) {
      int k = ks * 32 + i;
      float4 w4 = *(const float4*)&w2[k * 128 + eg * 4];
      float a0 = sm.hids[k], a1 = sm.hids[256 + k];
      acc[0][0] = fmaf(a0, w4.x, acc[0][0]); acc[0][1] = fmaf(a0, w4.y, acc[0][1]);
      acc[0][2] = fmaf(a0, w4.z, acc[0][2]); acc[0][3] = fmaf(a0, w4.w, acc[0][3]);
      acc[1][0] = fmaf(a1, w4.x, acc[1][0]); acc[1][1] = fmaf(a1, w4.y, acc[1][1]);
      acc[1][2] = fmaf(a1, w4.z, acc[1][2]); acc[1][3] = fmaf(a1, w4.w, acc[1][3]);
    }
    __syncthreads();
#pragma unroll
    for (int r = 0; r < 2; r++)
      *(float4*)&sm.red[ks * 256 + r * 128 + eg * 4] = *(float4*)acc[r];
  }
  __syncthreads();
  {
    float s = 0.0f;
#pragma unroll
    for (int ks = 0; ks < 8; ks++) s += sm.red[ks * 256 + tx];
    int r = tx >> 7, e = tx & 127;
    float v = s + b2[e];
    g_h[(row0 + r) * 128 + e] = v;
    g_hb[(row0 + r) * 128 + e] = f2b(v);
  }
}

// ---------------- Phase 2: K/Q/V projections via MFMA ---------------------------
__device__ __forceinline__ void phase_kqv(SM2& sm, int b, int tx,
    const float* __restrict__ bk, const float* __restrict__ bq,
    const float* __restrict__ bv) {
  int rt = b & 15, ph = b >> 4;
  int proj = ph >> 3, head = ph & 7;
  const float* Bb = (proj == 0) ? bk : (proj == 1) ? bq : bv;
  u16* O = (proj == 0) ? g_K : (proj == 1) ? g_Q : g_V;
  int r0 = rt * 64;
#pragma unroll
  for (int t = 0; t < 4; t++) {
    int idx = t * 256 + tx, row = idx >> 4, oct = idx & 15;
    *(uint4*)&sm.hs[row * 136 + oct * 8] = *(const uint4*)&g_hb[(r0 + row) * 128 + oct * 8];
  }
  const u16* Wtg = g_Wt + ph * 16384;
#pragma unroll
  for (int t = 0; t < 8; t++) {
    int idx = t * 256 + tx, row = idx >> 4, oct = idx & 15;
    *(uint4*)&sm.Wt[row * 136 + oct * 8] = *(const uint4*)&Wtg[row * 128 + oct * 8];
  }
  __syncthreads();
  int lane = tx & 63, wv_ = tx >> 6, cl = lane & 15, quad = lane >> 4;
  short8 bH[4];
#pragma unroll
  for (int kk = 0; kk < 4; kk++)
    bH[kk] = *(const short8*)&sm.hs[(wv_ * 16 + cl) * 136 + kk * 32 + quad * 8];
  f32x4 zero = {0.0f, 0.0f, 0.0f, 0.0f};
  f32x4 acc[8];
#pragma unroll
  for (int em = 0; em < 8; em++) acc[em] = zero;
#pragma unroll
  for (int em = 0; em < 8; em++)
#pragma unroll
    for (int kk = 0; kk < 4; kk++) {
      short8 aW = *(const short8*)&sm.Wt[(em * 16 + cl) * 136 + kk * 32 + quad * 8];
      acc[em] = __builtin_amdgcn_mfma_f32_16x16x32_bf16(aW, bH[kk], acc[em], 0, 0, 0);
    }
#pragma unroll
  for (int em = 0; em < 8; em++) {
    float4 b4 = *(const float4*)&Bb[head * 128 + em * 16 + quad * 4];
    uint2 st = make_uint2(pack2(acc[em][0] + b4.x, acc[em][1] + b4.y),
                          pack2(acc[em][2] + b4.z, acc[em][3] + b4.w));
    *(uint2*)&O[(head * 1024 + r0 + wv_ * 16 + cl) * 128 + em * 16 + quad * 4] = st;
  }
}

// ---------------- Phase 3: attention via MFMA, bf16 partials out ----------------
__device__ __forceinline__ void phase_attn(SM3& sm, int b, int tx) {
  int jc = b & 3, it = (b >> 2) & 7, hn = b >> 5;
  int i0 = it * 64;
  const u16* Kp = g_K + hn * 65536;
  const u16* Qp = g_Q + hn * 65536;
  const u16* Vp = g_V + hn * 65536;
#pragma unroll
  for (int t = 0; t < 4; t++) {
    int idx = t * 256 + tx, row = idx >> 4, oct = idx & 15;
    *(uint4*)&sm.Ks[row * 136 + oct * 8] = *(const uint4*)&Kp[(i0 + row) * 128 + oct * 8];
  }
  int lane = tx & 63, wv = tx >> 6;
  int cl = lane & 15, quad = lane >> 4;
  f32x4 zero = {0.0f, 0.0f, 0.0f, 0.0f};
  f32x4 o[8];
#pragma unroll
  for (int es = 0; es < 8; es++) o[es] = zero;
  float m_ = -1e30f, l_ = 0.0f;

  for (int jt = 0; jt < 2; jt++) {
    int j0 = jc * 128 + jt * 64;
    __syncthreads();
#pragma unroll
    for (int t = 0; t < 4; t++) {
      int idx = t * 256 + tx, row = idx >> 4, oct = idx & 15;
      *(uint4*)&sm.Qs[row * 136 + oct * 8] = *(const uint4*)&Qp[(j0 + row) * 128 + oct * 8];
    }
    {
      int jg = (tx & 15) * 4, e8 = (tx >> 4) * 8;
      uint4 r0 = *(const uint4*)&Vp[(j0 + jg + 0) * 128 + e8];
      uint4 r1 = *(const uint4*)&Vp[(j0 + jg + 1) * 128 + e8];
      uint4 r2 = *(const uint4*)&Vp[(j0 + jg + 2) * 128 + e8];
      uint4 r3 = *(const uint4*)&Vp[(j0 + jg + 3) * 128 + e8];
      const u32* p0 = (const u32*)&r0; const u32* p1 = (const u32*)&r1;
      const u32* p2 = (const u32*)&r2; const u32* p3 = (const u32*)&r3;
#pragma unroll
      for (int c = 0; c < 8; c++) {
        int w = c >> 1, sh = (c & 1) * 16;
        u32 lo = ((p0[w] >> sh) & 0xffffu) | (((p1[w] >> sh) & 0xffffu) << 16);
        u32 hi = ((p2[w] >> sh) & 0xffffu) | (((p3[w] >> sh) & 0xffffu) << 16);
        *(uint2*)&sm.Vt[(e8 + c) * 72 + jg] = make_uint2(lo, hi);
      }
    }
    __syncthreads();
    short8 bK[4];
#pragma unroll
    for (int kk = 0; kk < 4; kk++)
      bK[kk] = *(const short8*)&sm.Ks[(wv * 16 + cl) * 136 + kk * 32 + quad * 8];
    f32x4 st[4];
#pragma unroll
    for (int s = 0; s < 4; s++) {
      f32x4 acc = zero;
#pragma unroll
      for (int kk = 0; kk < 4; kk++) {
        short8 aQ = *(const short8*)&sm.Qs[(s * 16 + cl) * 136 + kk * 32 + quad * 8];
        acc = __builtin_amdgcn_mfma_f32_16x16x32_bf16(aQ, bK[kk], acc, 0, 0, 0);
      }
      st[s] = acc;
    }
    float p[4][4];
    float tm = -1e30f;
#pragma unroll
    for (int s = 0; s < 4; s++)
#pragma unroll
      for (int r = 0; r < 4; r++) {
        float v = st[s][r];
        v = fmaxf(v, 0.2f * v);
        p[s][r] = v;
        tm = fmaxf(tm, v);
      }
    tm = fmaxf(tm, __shfl_xor(tm, 16));
    tm = fmaxf(tm, __shfl_xor(tm, 32));
    float mn = fmaxf(m_, tm);
    float alpha = __expf(m_ - mn);
    m_ = mn;
    float ps = 0.0f;
#pragma unroll
    for (int s = 0; s < 4; s++)
#pragma unroll
      for (int r = 0; r < 4; r++) {
        float e = __expf(p[s][r] - mn);
        p[s][r] = e;
        ps += e;
      }
    ps += __shfl_xor(ps, 16);
    ps += __shfl_xor(ps, 32);
    l_ = l_ * alpha + ps;
#pragma unroll
    for (int s = 0; s < 4; s++) {
      uint2 w2v = make_uint2(pack2(p[s][0], p[s][1]), pack2(p[s][2], p[s][3]));
      *(uint2*)&sm.Pw[(wv * 16 + cl) * 72 + s * 16 + quad * 4] = w2v;
    }
    if (quad == 0) sm.alphas[wv * 16 + cl] = alpha;
    __syncthreads();
    f32x4 av = *(const f32x4*)&sm.alphas[wv * 16 + quad * 4];
#pragma unroll
    for (int es = 0; es < 8; es++) o[es] *= av;
    short8 aP[2];
#pragma unroll
    for (int k2 = 0; k2 < 2; k2++)
      aP[k2] = *(const short8*)&sm.Pw[(wv * 16 + cl) * 72 + k2 * 32 + quad * 8];
#pragma unroll
    for (int es = 0; es < 8; es++) {
#pragma unroll
      for (int k2 = 0; k2 < 2; k2++) {
        short8 bV = *(const short8*)&sm.Vt[(es * 16 + cl) * 72 + k2 * 32 + quad * 8];
        o[es] = __builtin_amdgcn_mfma_f32_16x16x32_bf16(aP[k2], bV, o[es], 0, 0, 0);
      }
    }
  }
#pragma unroll
  for (int es = 0; es < 8; es++)
#pragma unroll
    for (int r = 0; r < 4; r++)
      g_Opb[(b * 64 + wv * 16 + quad * 4 + r) * 128 + es * 16 + cl] = f2b(o[es][r]);
  if (quad == 0) {
    g_ml[(b * 64 + wv * 16 + cl) * 2 + 0] = m_;
    g_ml[(b * 64 + wv * 16 + cl) * 2 + 1] = l_;
  }
}

// ---------------- Phase 4: merge + fv MLP + residual + A/B (weights from L2) ----
__device__ __forceinline__ void phase_fv(SMfv& sm, int b, int tx,
    const float* __restrict__ fv_b1, const float* __restrict__ fv_b2,
    const float* __restrict__ fe_b1, float* __restrict__ x2out) {
  int r0 = b * 16;
  // A. merge 4 flash partials -> atts (normalized + leaky, bf16)
  {
    int task = tx >> 1, half = tx & 1;           // 128 tasks = 16 rows x 8 heads
    int lr = task >> 3, head = task & 7;
    int gr = r0 + lr;
    int n = gr >> 9, i = gr & 511;
    int it = i >> 6, lr64 = i & 63;
    int hn = head * 2 + n;
    int mlbase = (hn * 32 + it * 4) * 64 + lr64;
    float mc[4], lc[4];
#pragma unroll
    for (int c = 0; c < 4; c++) {
      float2 ml = *(const float2*)&g_ml[(mlbase + c * 64) * 2];
      mc[c] = ml.x; lc[c] = ml.y;
    }
    float ms = fmaxf(fmaxf(mc[0], mc[1]), fmaxf(mc[2], mc[3]));
    float lsum = 0.0f;
    float ra[64];
#pragma unroll
    for (int i2 = 0; i2 < 64; i2++) ra[i2] = 0.0f;
#pragma unroll
    for (int c = 0; c < 4; c++) {
      float w = __expf(mc[c] - ms);
      lsum += w * lc[c];
      const u16* src = &g_Opb[(mlbase + c * 64) * 128 + half * 64];
#pragma unroll
      for (int ov = 0; ov < 8; ov++) {
        uint4 v = *(const uint4*)&src[ov * 8];
        ra[ov * 8 + 0] = fmaf(w, lo16(v.x), ra[ov * 8 + 0]);
        ra[ov * 8 + 1] = fmaf(w, hi16(v.x), ra[ov * 8 + 1]);
        ra[ov * 8 + 2] = fmaf(w, lo16(v.y), ra[ov * 8 + 2]);
        ra[ov * 8 + 3] = fmaf(w, hi16(v.y), ra[ov * 8 + 3]);
        ra[ov * 8 + 4] = fmaf(w, lo16(v.z), ra[ov * 8 + 4]);
        ra[ov * 8 + 5] = fmaf(w, hi16(v.z), ra[ov * 8 + 5]);
        ra[ov * 8 + 6] = fmaf(w, lo16(v.w), ra[ov * 8 + 6]);
        ra[ov * 8 + 7] = fmaf(w, hi16(v.w), ra[ov * 8 + 7]);
      }
    }
    float inv = 1.0f / lsum;
    u32 pk[32];
#pragma unroll
    for (int i2 = 0; i2 < 32; i2++) {
      float v0 = ra[i2 * 2] * inv;     v0 = fmaxf(v0, 0.2f * v0);
      float v1 = ra[i2 * 2 + 1] * inv; v1 = fmaxf(v1, 0.2f * v1);
      pk[i2] = pack2(v0, v1);
    }
    int dst = lr * 1032 + head * 128 + half * 64;
#pragma unroll
    for (int ov = 0; ov < 8; ov++)
      *(uint4*)&sm.atts[dst + ov * 8] =
          make_uint4(pk[ov * 4], pk[ov * 4 + 1], pk[ov * 4 + 2], pk[ov * 4 + 3]);
  }
  __syncthreads();

  int lane = tx & 63, w = tx >> 6, cl = lane & 15, quad = lane >> 4;
  f32x4 zero = {0.0f, 0.0f, 0.0f, 0.0f};
  int e0 = (2 * w) * 16 + cl, e1 = (2 * w + 1) * 16 + cl;

  // B. hid = atts @ fv_w1 (K=1024); weight fragments straight from L2
  f32x4 accH[2] = {zero, zero};
#pragma unroll 2
  for (int kc = 0; kc < 8; kc++) {
    short8 bA[4];
#pragma unroll
    for (int kk = 0; kk < 4; kk++)
      bA[kk] = *(const short8*)&sm.atts[cl * 1032 + kc * 128 + kk * 32 + quad * 8];
#pragma unroll
    for (int kk = 0; kk < 4; kk++) {
      short8 aW0 = *(const short8*)&g_w1t[e0 * 1024 + kc * 128 + kk * 32 + quad * 8];
      short8 aW1 = *(const short8*)&g_w1t[e1 * 1024 + kc * 128 + kk * 32 + quad * 8];
      accH[0] = __builtin_amdgcn_mfma_f32_16x16x32_bf16(aW0, bA[kk], accH[0], 0, 0, 0);
      accH[1] = __builtin_amdgcn_mfma_f32_16x16x32_bf16(aW1, bA[kk], accH[1], 0, 0, 0);
    }
  }
  // C. hid epilogue (bias+relu -> bf16 LDS)
#pragma unroll
  for (int t2 = 0; t2 < 2; t2++) {
    int eb = (2 * w + t2) * 16 + quad * 4;
    float4 b4 = *(const float4*)&fv_b1[eb];
    float v0 = fmaxf(accH[t2][0] + b4.x, 0.0f);
    float v1 = fmaxf(accH[t2][1] + b4.y, 0.0f);
    float v2 = fmaxf(accH[t2][2] + b4.z, 0.0f);
    float v3 = fmaxf(accH[t2][3] + b4.w, 0.0f);
    *(u32*)&sm.hidb[cl * 136 + eb] = pack2(v0, v1);
    *(u32*)&sm.hidb[cl * 136 + eb + 2] = pack2(v2, v3);
  }
  __syncthreads();
  // D. x2 = hid @ fv_w2 + b2 + h; write x2out; x2 -> bf16 LDS
  {
    short8 bH2[4];
#pragma unroll
    for (int kk = 0; kk < 4; kk++)
      bH2[kk] = *(const short8*)&sm.hidb[cl * 136 + kk * 32 + quad * 8];
    int gr = r0 + cl;
#pragma unroll
    for (int t2 = 0; t2 < 2; t2++) {
      int em = 2 * w + t2, er = em * 16 + cl;
      f32x4 acc2 = zero;
#pragma unroll
      for (int kk = 0; kk < 4; kk++) {
        short8 aW = *(const short8*)&g_w2t[er * 128 + kk * 32 + quad * 8];
        acc2 = __builtin_amdgcn_mfma_f32_16x16x32_bf16(aW, bH2[kk], acc2, 0, 0, 0);
      }
      int eb = em * 16 + quad * 4;
      float4 b4 = *(const float4*)&fv_b2[eb];
      float4 h4 = *(const float4*)&g_h[gr * 128 + eb];
      float4 xv;
      xv.x = acc2[0] + b4.x + h4.x;
      xv.y = acc2[1] + b4.y + h4.y;
      xv.z = acc2[2] + b4.z + h4.z;
      xv.w = acc2[3] + b4.w + h4.w;
      *(float4*)&x2out[gr * 128 + eb] = xv;
      *(u32*)&sm.x2b[cl * 136 + eb] = pack2(xv.x, xv.y);
      *(u32*)&sm.x2b[cl * 136 + eb + 2] = pack2(xv.z, xv.w);
    }
  }
  __syncthreads();
  // E/F. A = x2 @ feA + fe_b1 ; B = x2 @ feB
  short8 bX[4];
#pragma unroll
  for (int kk = 0; kk < 4; kk++)
    bX[kk] = *(const short8*)&sm.x2b[cl * 136 + kk * 32 + quad * 8];
  {
    int gr = r0 + cl;
#pragma unroll
    for (int t2 = 0; t2 < 2; t2++) {
      int em = 2 * w + t2, er = em * 16 + cl;
      f32x4 accA = zero, accB = zero;
#pragma unroll
      for (int kk = 0; kk < 4; kk++) {
        short8 aWA = *(const short8*)&g_fat[er * 128 + kk * 32 + quad * 8];
        short8 aWB = *(const short8*)&g_fat[16384 + er * 128 + kk * 32 + quad * 8];
        accA = __builtin_amdgcn_mfma_f32_16x16x32_bf16(aWA, bX[kk], accA, 0, 0, 0);
        accB = __builtin_amdgcn_mfma_f32_16x16x32_bf16(aWB, bX[kk], accB, 0, 0, 0);
      }
      int eb = em * 16 + quad * 4;
      float4 b4 = *(const float4*)&fe_b1[eb];
      float4 av;
      av.x = accA[0] + b4.x; av.y = accA[1] + b4.y;
      av.z = accA[2] + b4.z; av.w = accA[3] + b4.w;
      *(float4*)&g_A[gr * 128 + eb] = av;
      *(f32x4*)&g_Bm[gr * 128 + eb] = accB;
    }
  }
}

// ---------------- Phase 5: pairwise edge FFN (A_i + B_j factorized) -------------
__device__ __forceinline__ void phase_edge(SM6& sm, int b, int tx,
    const float* __restrict__ few2, const float* __restrict__ feb2,
    float* __restrict__ edge) {
  int n = b >> 8, rest = b & 255, ig = rest >> 1, jh = rest & 1;
  int i0 = ig * 4;
  if (tx < 128) sm.w2s[tx] = few2[tx];
  sm.As[tx] = g_A[(n * 512 + i0) * 128 + tx];
  sm.As[tx + 256] = g_A[(n * 512 + i0) * 128 + tx + 256];
  float eb2 = feb2[0];
  __syncthreads();
  int j = jh * 256 + tx;
  const float* B0 = &g_Bm[(n * 512 + j) * 128];
  float acc[4] = {};
#pragma unroll 4
  for (int dc = 0; dc < 32; dc++) {
    float4 bv = *(const float4*)&B0[dc * 4];
    float4 w4 = *(const float4*)&sm.w2s[dc * 4];
#pragma unroll
    for (int i = 0; i < 4; i++) {
      float4 a4 = *(const float4*)&sm.As[i * 128 + dc * 4];
      acc[i] = fmaf(fmaxf(a4.x + bv.x, 0.0f), w4.x, acc[i]);
      acc[i] = fmaf(fmaxf(a4.y + bv.y, 0.0f), w4.y, acc[i]);
      acc[i] = fmaf(fmaxf(a4.z + bv.z, 0.0f), w4.z, acc[i]);
      acc[i] = fmaf(fmaxf(a4.w + bv.w, 0.0f), w4.w, acc[i]);
    }
  }
  const float scale = 1.0f / 512.0f;
#pragma unroll
  for (int i = 0; i < 4; i++)
    edge[(n * 512 + i0 + i) * 512 + j] = (acc[i] + eb2) * scale;
}

// ---------------- Kernel A: fnode -> bar -> kqv -> bar -> attn ------------------
__global__ __launch_bounds__(256, 2) void k_front(
    const float* __restrict__ x, const float* __restrict__ fn_w1,
    const float* __restrict__ fn_b1, const float* __restrict__ fn_w2,
    const float* __restrict__ fn_b2, const float* __restrict__ wk,
    const float* __restrict__ bk, const float* __restrict__ wq,
    const float* __restrict__ bq, const float* __restrict__ wv,
    const float* __restrict__ bv, const float* __restrict__ fv_w1,
    const float* __restrict__ fv_w2, const float* __restrict__ fe_w1) {
  __shared__ SMA sm;
  int b = blockIdx.x, tx = threadIdx.x;
  u32 gen = 0;
  phase_fnode(sm.p1, b, tx, x, fn_w1, fn_b1, fn_w2, fn_b2, wk, wq, wv,
              fv_w1, fv_w2, fe_w1);
  gbar(&g_c1, gen, false);
  if (b < 384) phase_kqv(sm.p2, b, tx, bk, bq, bv);
  gbar(&g_c2, gen, true);
  phase_attn(sm.p3, b, tx);
}

// ---------------- Kernel B: fv -> bar -> edge -----------------------------------
__global__ __launch_bounds__(256, 2) void k_back(
    const float* __restrict__ fv_b1, const float* __restrict__ fv_b2,
    const float* __restrict__ fe_b1, const float* __restrict__ few2,
    const float* __restrict__ feb2, float* __restrict__ x2out,
    float* __restrict__ edge) {
  __shared__ SMB sm;
  int b = blockIdx.x, tx = threadIdx.x;
  u32 gen = 0;
  if (b < 64) phase_fv(sm.pf, b, tx, fv_b1, fv_b2, fe_b1, x2out);
  gbar(&g_c3, gen, false);
  phase_edge(sm.p6, b, tx, few2, feb2, edge);
}

extern "C" void kernel_launch(void* const* d_in, const int* in_sizes, int n_in,
                              void* d_out, int out_size, void* d_ws, size_t ws_size,
                              hipStream_t stream) {
  (void)in_sizes; (void)n_in; (void)out_size; (void)d_ws; (void)ws_size;
  const float* x     = (const float*)d_in[0];
  const float* fn_w1 = (const float*)d_in[1];
  const float* fn_b1 = (const float*)d_in[2];
  const float* fn_w2 = (const float*)d_in[3];
  const float* fn_b2 = (const float*)d_in[4];
  const float* wk    = (const float*)d_in[5];
  const float* bk    = (const float*)d_in[6];
  const float* wq    = (const float*)d_in[7];
  const float* bq    = (const float*)d_in[8];
  const float* wv    = (const float*)d_in[9];
  const float* bv    = (const float*)d_in[10];
  const float* fv_w1 = (const float*)d_in[11];
  const float* fv_b1 = (const float*)d_in[12];
  const float* fv_w2 = (const float*)d_in[13];
  const float* fv_b2 = (const float*)d_in[14];
  const float* fe_w1 = (const float*)d_in[15];
  const float* fe_b1 = (const float*)d_in[16];
  const float* fe_w2 = (const float*)d_in[17];
  const float* fe_b2 = (const float*)d_in[18];

  float* x2out = (float*)d_out;      // [0, 131072) floats
  float* edge  = x2out + 131072;     // [131072, 655360) floats

  k_front<<<512, 256, 0, stream>>>(x, fn_w1, fn_b1, fn_w2, fn_b2, wk, bk, wq, bq,
                                   wv, bv, fv_w1, fv_w2, fe_w1);
  k_back<<<512, 256, 0, stream>>>(fv_b1, fv_b2, fe_b1, fe_w2, fe_b2, x2out, edge);
}

// Round 5
// 179.635 us; speedup vs baseline: 1.9649x; 1.9649x over previous
//
#include <hip/hip_runtime.h>

typedef unsigned short u16;
typedef unsigned int u32;
typedef __attribute__((ext_vector_type(8))) short short8;
typedef __attribute__((ext_vector_type(4))) float f32x4;

__device__ __forceinline__ u16 f2b(float f) {
  union { float f; u32 i; } v; v.f = f;
  u32 i = v.i;
  return (u16)((i + 0x7FFFu + ((i >> 16) & 1u)) >> 16);
}
__device__ __forceinline__ float lo16(u32 x) { union { u32 i; float f; } v; v.i = x << 16; return v.f; }
__device__ __forceinline__ float hi16(u32 x) { union { u32 i; float f; } v; v.i = x & 0xffff0000u; return v.f; }
__device__ __forceinline__ u32 pack2(float a, float b) { return (u32)f2b(a) | ((u32)f2b(b) << 16); }

// Sizes: N=2, M=512, D_IN=64, D=128, H=8. Rows = N*M = 1024. hn = h*2+n in [0,16).
__device__ __align__(16) float g_h[1024 * 128];
__device__ __align__(16) u16   g_hb[1024 * 128];
__device__ __align__(16) u16   g_Wt[24 * 128 * 128];   // W^T per (proj,head): [ph][e][d] bf16
__device__ __align__(16) u16   g_w1t[128 * 1024];      // fv_w1^T: [e][k] bf16
__device__ __align__(16) u16   g_w2t[128 * 128];       // fv_w2^T: [e][k] bf16
__device__ __align__(16) u16   g_fat[2 * 128 * 128];   // fe_w1^T halves: [half][e][k] bf16
__device__ __align__(16) u16   g_Opb[512 * 64 * 128];  // bf16 flash partials
__device__ __align__(16) float g_ml[512 * 64 * 2];
__device__ __align__(16) float g_A[1024 * 128];
__device__ __align__(16) float g_Bm[1024 * 128];

// ---------------- Kernel 1: f_node (+ weight pre-transpose piggyback) ------------
__global__ void k_fnode(const float* __restrict__ x, const float* __restrict__ w1,
                        const float* __restrict__ b1, const float* __restrict__ w2,
                        const float* __restrict__ b2, const float* __restrict__ wk,
                        const float* __restrict__ wq, const float* __restrict__ wv,
                        const float* __restrict__ fvw1, const float* __restrict__ fvw2,
                        const float* __restrict__ few1) {
  __shared__ float xr[2 * 64];
  __shared__ float hids[2 * 256];
  __shared__ float red[2048];
  int tx = threadIdx.x;
  int row0 = blockIdx.x * 2;
  if (tx < 128) {
    int r = tx >> 6, k = tx & 63;
    xr[tx] = x[(row0 + r) * 64 + k] + sinf((float)k * (5.0f / 63.0f));
  }
  // piggyback: transpose all MFMA-consumed weights to bf16
  {
    int base = blockIdx.x * 1280 + tx;
#pragma unroll
    for (int t = 0; t < 5; t++) {
      int idx = base + t * 256;
      if (idx < 393216) {
        int ph = idx >> 14, rem = idx & 16383, e = rem >> 7, d = rem & 127;
        int proj = ph >> 3, head = ph & 7;
        const float* W = (proj == 0) ? wk : (proj == 1) ? wq : wv;
        g_Wt[idx] = f2b(W[head * 16384 + d * 128 + e]);
      } else if (idx < 524288) {
        int idx2 = idx - 393216;          // fv_w1^T
        int e = idx2 >> 10, k = idx2 & 1023;
        g_w1t[idx2] = f2b(fvw1[k * 128 + e]);
      } else if (idx < 540672) {
        int idx3 = idx - 524288;          // fv_w2^T
        int e = idx3 >> 7, k = idx3 & 127;
        g_w2t[idx3] = f2b(fvw2[k * 128 + e]);
      } else if (idx < 573440) {
        int idx4 = idx - 540672;          // fe_w1^T halves
        int half = idx4 >> 14, rem = idx4 & 16383;
        int e = rem >> 7, k = rem & 127;
        g_fat[idx4] = f2b(few1[(half * 128 + k) * 128 + e]);
      }
    }
  }
  __syncthreads();
  {
    int ks = tx >> 6, cg = tx & 63;
    float acc[2][4] = {};
#pragma unroll 4
    for (int i = 0; i < 16; i++) {
      int k = ks * 16 + i;
      float4 w4 = *(const float4*)&w1[k * 256 + cg * 4];
      float a0 = xr[k], a1 = xr[64 + k];
      acc[0][0] = fmaf(a0, w4.x, acc[0][0]); acc[0][1] = fmaf(a0, w4.y, acc[0][1]);
      acc[0][2] = fmaf(a0, w4.z, acc[0][2]); acc[0][3] = fmaf(a0, w4.w, acc[0][3]);
      acc[1][0] = fmaf(a1, w4.x, acc[1][0]); acc[1][1] = fmaf(a1, w4.y, acc[1][1]);
      acc[1][2] = fmaf(a1, w4.z, acc[1][2]); acc[1][3] = fmaf(a1, w4.w, acc[1][3]);
    }
#pragma unroll
    for (int r = 0; r < 2; r++)
      *(float4*)&red[ks * 512 + r * 256 + cg * 4] = *(float4*)acc[r];
  }
  __syncthreads();
#pragma unroll
  for (int jo = 0; jo < 2; jo++) {
    int o = jo * 256 + tx;
    float s = red[o] + red[512 + o] + red[1024 + o] + red[1536 + o];
    hids[o] = fmaxf(s + b1[o & 255], 0.0f);
  }
  __syncthreads();
  {
    int ks = tx >> 5, eg = tx & 31;
    float acc[2][4] = {};
#pragma unroll 4
    for (int i = 0; i < 32; i++) {
      int k = ks * 32 + i;
      float4 w4 = *(const float4*)&w2[k * 128 + eg * 4];
      float a0 = hids[k], a1 = hids[256 + k];
      acc[0][0] = fmaf(a0, w4.x, acc[0][0]); acc[0][1] = fmaf(a0, w4.y, acc[0][1]);
      acc[0][2] = fmaf(a0, w4.z, acc[0][2]); acc[0][3] = fmaf(a0, w4.w, acc[0][3]);
      acc[1][0] = fmaf(a1, w4.x, acc[1][0]); acc[1][1] = fmaf(a1, w4.y, acc[1][1]);
      acc[1][2] = fmaf(a1, w4.z, acc[1][2]); acc[1][3] = fmaf(a1, w4.w, acc[1][3]);
    }
    __syncthreads();
#pragma unroll
    for (int r = 0; r < 2; r++)
      *(float4*)&red[ks * 256 + r * 128 + eg * 4] = *(float4*)acc[r];
  }
  __syncthreads();
  {
    float s = 0.0f;
#pragma unroll
    for (int ks = 0; ks < 8; ks++) s += red[ks * 256 + tx];
    int r = tx >> 7, e = tx & 127;
    float v = s + b2[e];
    g_h[(row0 + r) * 128 + e] = v;
    g_hb[(row0 + r) * 128 + e] = f2b(v);
  }
}

// ---------------- Kernel 2: fused K/Q/V projection + flash attention -------------
// Block (hn, it, jc) projects its own K tile (64 i-rows) and, per jt, its own
// Q/V tiles (64 j-rows) via MFMA reading g_hb/g_Wt straight from L2 — no
// g_K/g_Q/g_V globals, no kqv kernel, no extra boundary. Recompute is cheap
// (MFMA); sync is expensive (measured: ~20us/boundary, ~60-90us/grid-barrier).
__global__ __launch_bounds__(256) void k_qattn(
    const float* __restrict__ bk, const float* __restrict__ bq,
    const float* __restrict__ bv) {
  __shared__ union { u16 Ks[64 * 136]; u16 Pw[64 * 72]; } kp;  // Pw aliases Ks
  __shared__ u16 Qs[64 * 136];
  __shared__ u16 Vt[128 * 72];
  __shared__ float alphas[64];
  int b = blockIdx.x, tx = threadIdx.x;
  int jc = b & 3, it = (b >> 2) & 7, hn = b >> 5;
  int head = hn >> 1, n = hn & 1;
  int i0 = it * 64;
  int lane = tx & 63, wv = tx >> 6, cl = lane & 15, quad = lane >> 4;
  const u16* WtK = g_Wt + (head) * 16384;
  const u16* WtQ = g_Wt + (8 + head) * 16384;
  const u16* WtV = g_Wt + (16 + head) * 16384;
  f32x4 zero = {0.0f, 0.0f, 0.0f, 0.0f};

  // ---- K projection: rows i0..i0+63 -> Ks (bf16, row-major) ----
  {
    const u16* hbK = &g_hb[(n * 512 + i0 + wv * 16 + cl) * 128];
    short8 bH[4];
#pragma unroll
    for (int kk = 0; kk < 4; kk++)
      bH[kk] = *(const short8*)&hbK[kk * 32 + quad * 8];
    f32x4 acc[8];
#pragma unroll
    for (int em = 0; em < 8; em++) acc[em] = zero;
#pragma unroll
    for (int em = 0; em < 8; em++)
#pragma unroll
      for (int kk = 0; kk < 4; kk++) {
        short8 aW = *(const short8*)&WtK[(em * 16 + cl) * 128 + kk * 32 + quad * 8];
        acc[em] = __builtin_amdgcn_mfma_f32_16x16x32_bf16(aW, bH[kk], acc[em], 0, 0, 0);
      }
#pragma unroll
    for (int em = 0; em < 8; em++) {
      float4 b4 = *(const float4*)&bk[head * 128 + em * 16 + quad * 4];
      int addr = (wv * 16 + cl) * 136 + em * 16 + quad * 4;
      *(u32*)&kp.Ks[addr] = pack2(acc[em][0] + b4.x, acc[em][1] + b4.y);
      *(u32*)&kp.Ks[addr + 2] = pack2(acc[em][2] + b4.z, acc[em][3] + b4.w);
    }
  }
  __syncthreads();
  // hoist K fragments to registers; Ks LDS is then dead (Pw aliases it)
  short8 bK[4];
#pragma unroll
  for (int kk = 0; kk < 4; kk++)
    bK[kk] = *(const short8*)&kp.Ks[(wv * 16 + cl) * 136 + kk * 32 + quad * 8];

  f32x4 o[8];
#pragma unroll
  for (int es = 0; es < 8; es++) o[es] = zero;
  float m_ = -1e30f, l_ = 0.0f;

  for (int jt = 0; jt < 2; jt++) {
    int j0 = jc * 128 + jt * 64;
    __syncthreads();   // prior PV done with Qs/Vt; bK in regs (jt==0)
    // ---- Q projection: rows j0..j0+63 -> Qs ----
    {
      const u16* hbQ = &g_hb[(n * 512 + j0 + wv * 16 + cl) * 128];
      short8 bH[4];
#pragma unroll
      for (int kk = 0; kk < 4; kk++)
        bH[kk] = *(const short8*)&hbQ[kk * 32 + quad * 8];
      f32x4 acc[8];
#pragma unroll
      for (int em = 0; em < 8; em++) acc[em] = zero;
#pragma unroll
      for (int em = 0; em < 8; em++)
#pragma unroll
        for (int kk = 0; kk < 4; kk++) {
          short8 aW = *(const short8*)&WtQ[(em * 16 + cl) * 128 + kk * 32 + quad * 8];
          acc[em] = __builtin_amdgcn_mfma_f32_16x16x32_bf16(aW, bH[kk], acc[em], 0, 0, 0);
        }
#pragma unroll
      for (int em = 0; em < 8; em++) {
        float4 b4 = *(const float4*)&bq[head * 128 + em * 16 + quad * 4];
        int addr = (wv * 16 + cl) * 136 + em * 16 + quad * 4;
        *(u32*)&Qs[addr] = pack2(acc[em][0] + b4.x, acc[em][1] + b4.y);
        *(u32*)&Qs[addr + 2] = pack2(acc[em][2] + b4.z, acc[em][3] + b4.w);
      }
    }
    // ---- V projection: rows j0..j0+63 -> Vt (transposed: [e][jlocal]) ----
    {
      const u16* hbV = &g_hb[(n * 512 + j0 + wv * 16 + cl) * 128];
      short8 bH[4];
#pragma unroll
      for (int kk = 0; kk < 4; kk++)
        bH[kk] = *(const short8*)&hbV[kk * 32 + quad * 8];
      f32x4 acc[8];
#pragma unroll
      for (int em = 0; em < 8; em++) acc[em] = zero;
#pragma unroll
      for (int em = 0; em < 8; em++)
#pragma unroll
        for (int kk = 0; kk < 4; kk++) {
          short8 aW = *(const short8*)&WtV[(em * 16 + cl) * 128 + kk * 32 + quad * 8];
          acc[em] = __builtin_amdgcn_mfma_f32_16x16x32_bf16(aW, bH[kk], acc[em], 0, 0, 0);
        }
      int jl = wv * 16 + cl;
#pragma unroll
      for (int em = 0; em < 8; em++) {
        float4 b4 = *(const float4*)&bv[head * 128 + em * 16 + quad * 4];
        Vt[(em * 16 + quad * 4 + 0) * 72 + jl] = f2b(acc[em][0] + b4.x);
        Vt[(em * 16 + quad * 4 + 1) * 72 + jl] = f2b(acc[em][1] + b4.y);
        Vt[(em * 16 + quad * 4 + 2) * 72 + jl] = f2b(acc[em][2] + b4.z);
        Vt[(em * 16 + quad * 4 + 3) * 72 + jl] = f2b(acc[em][3] + b4.w);
      }
    }
    __syncthreads();
    // ---- QK^T, online softmax, PV (unchanged, verified) ----
    f32x4 st[4];
#pragma unroll
    for (int s = 0; s < 4; s++) {
      f32x4 acc = zero;
#pragma unroll
      for (int kk = 0; kk < 4; kk++) {
        short8 aQ = *(const short8*)&Qs[(s * 16 + cl) * 136 + kk * 32 + quad * 8];
        acc = __builtin_amdgcn_mfma_f32_16x16x32_bf16(aQ, bK[kk], acc, 0, 0, 0);
      }
      st[s] = acc;
    }
    float p[4][4];
    float tm = -1e30f;
#pragma unroll
    for (int s = 0; s < 4; s++)
#pragma unroll
      for (int r = 0; r < 4; r++) {
        float v = st[s][r];
        v = fmaxf(v, 0.2f * v);
        p[s][r] = v;
        tm = fmaxf(tm, v);
      }
    tm = fmaxf(tm, __shfl_xor(tm, 16));
    tm = fmaxf(tm, __shfl_xor(tm, 32));
    float mn = fmaxf(m_, tm);
    float alpha = __expf(m_ - mn);
    m_ = mn;
    float ps = 0.0f;
#pragma unroll
    for (int s = 0; s < 4; s++)
#pragma unroll
      for (int r = 0; r < 4; r++) {
        float e = __expf(p[s][r] - mn);
        p[s][r] = e;
        ps += e;
      }
    ps += __shfl_xor(ps, 16);
    ps += __shfl_xor(ps, 32);
    l_ = l_ * alpha + ps;
#pragma unroll
    for (int s = 0; s < 4; s++) {
      uint2 w2v = make_uint2(pack2(p[s][0], p[s][1]), pack2(p[s][2], p[s][3]));
      *(uint2*)&kp.Pw[(wv * 16 + cl) * 72 + s * 16 + quad * 4] = w2v;
    }
    if (quad == 0) alphas[wv * 16 + cl] = alpha;
    __syncthreads();
    f32x4 av = *(const f32x4*)&alphas[wv * 16 + quad * 4];
#pragma unroll
    for (int es = 0; es < 8; es++) o[es] *= av;
    short8 aP[2];
#pragma unroll
    for (int k2 = 0; k2 < 2; k2++)
      aP[k2] = *(const short8*)&kp.Pw[(wv * 16 + cl) * 72 + k2 * 32 + quad * 8];
#pragma unroll
    for (int es = 0; es < 8; es++) {
#pragma unroll
      for (int k2 = 0; k2 < 2; k2++) {
        short8 bV = *(const short8*)&Vt[(es * 16 + cl) * 72 + k2 * 32 + quad * 8];
        o[es] = __builtin_amdgcn_mfma_f32_16x16x32_bf16(aP[k2], bV, o[es], 0, 0, 0);
      }
    }
  }
#pragma unroll
  for (int es = 0; es < 8; es++)
#pragma unroll
    for (int r = 0; r < 4; r++)
      g_Opb[(b * 64 + wv * 16 + quad * 4 + r) * 128 + es * 16 + cl] = f2b(o[es][r]);
  if (quad == 0) {
    g_ml[(b * 64 + wv * 16 + cl) * 2 + 0] = m_;
    g_ml[(b * 64 + wv * 16 + cl) * 2 + 1] = l_;
  }
}

// ---------------- Kernel 3: merge + fv MLP + residual + A/B (512 thr, 8 waves) --
__global__ __launch_bounds__(512) void k_fv(
    const float* __restrict__ fv_b1, const float* __restrict__ fv_b2,
    const float* __restrict__ fe_b1, float* __restrict__ x2out) {
  __shared__ u16 atts[16 * 1032];   // row stride 1032 (pad 8)
  __shared__ u16 hidb[16 * 136];
  __shared__ u16 x2b[16 * 136];
  int b = blockIdx.x, tx = threadIdx.x;
  int r0 = b * 16;

  // A. merge 4 flash partials -> atts (normalized + leaky, bf16)
  {
    int task = tx >> 2, q4 = tx & 3;             // 128 tasks x 4 e-quarters
    int lr = task >> 3, head = task & 7;
    int gr = r0 + lr;
    int n = gr >> 9, i = gr & 511;
    int it = i >> 6, lr64 = i & 63;
    int hn = head * 2 + n;
    int mlbase = (hn * 32 + it * 4) * 64 + lr64;
    float mc[4], lc[4];
#pragma unroll
    for (int c = 0; c < 4; c++) {
      float2 ml = *(const float2*)&g_ml[(mlbase + c * 64) * 2];
      mc[c] = ml.x; lc[c] = ml.y;
    }
    float ms = fmaxf(fmaxf(mc[0], mc[1]), fmaxf(mc[2], mc[3]));
    float lsum = 0.0f;
    float ra[32];
#pragma unroll
    for (int i2 = 0; i2 < 32; i2++) ra[i2] = 0.0f;
#pragma unroll
    for (int c = 0; c < 4; c++) {
      float w = __expf(mc[c] - ms);
      lsum += w * lc[c];
      const u16* src = &g_Opb[(mlbase + c * 64) * 128 + q4 * 32];
#pragma unroll
      for (int ov = 0; ov < 4; ov++) {
        uint4 v = *(const uint4*)&src[ov * 8];
        ra[ov * 8 + 0] = fmaf(w, lo16(v.x), ra[ov * 8 + 0]);
        ra[ov * 8 + 1] = fmaf(w, hi16(v.x), ra[ov * 8 + 1]);
        ra[ov * 8 + 2] = fmaf(w, lo16(v.y), ra[ov * 8 + 2]);
        ra[ov * 8 + 3] = fmaf(w, hi16(v.y), ra[ov * 8 + 3]);
        ra[ov * 8 + 4] = fmaf(w, lo16(v.z), ra[ov * 8 + 4]);
        ra[ov * 8 + 5] = fmaf(w, hi16(v.z), ra[ov * 8 + 5]);
        ra[ov * 8 + 6] = fmaf(w, lo16(v.w), ra[ov * 8 + 6]);
        ra[ov * 8 + 7] = fmaf(w, hi16(v.w), ra[ov * 8 + 7]);
      }
    }
    float inv = 1.0f / lsum;
    u32 pk[16];
#pragma unroll
    for (int i2 = 0; i2 < 16; i2++) {
      float v0 = ra[i2 * 2] * inv;     v0 = fmaxf(v0, 0.2f * v0);
      float v1 = ra[i2 * 2 + 1] * inv; v1 = fmaxf(v1, 0.2f * v1);
      pk[i2] = pack2(v0, v1);
    }
    int dst = lr * 1032 + head * 128 + q4 * 32;
#pragma unroll
    for (int ov = 0; ov < 4; ov++)
      *(uint4*)&atts[dst + ov * 8] =
          make_uint4(pk[ov * 4], pk[ov * 4 + 1], pk[ov * 4 + 2], pk[ov * 4 + 3]);
  }
  __syncthreads();

  int lane = tx & 63, w = tx >> 6, cl = lane & 15, quad = lane >> 4;
  f32x4 zero = {0.0f, 0.0f, 0.0f, 0.0f};

  // B. hid = atts @ fv_w1 (K=1024); wave w owns em = w; weights from L2
  f32x4 accH = zero;
#pragma unroll 2
  for (int kc = 0; kc < 8; kc++) {
    short8 bA[4];
#pragma unroll
    for (int kk = 0; kk < 4; kk++)
      bA[kk] = *(const short8*)&atts[cl * 1032 + kc * 128 + kk * 32 + quad * 8];
#pragma unroll
    for (int kk = 0; kk < 4; kk++) {
      short8 aW = *(const short8*)&g_w1t[(w * 16 + cl) * 1024 + kc * 128 + kk * 32 + quad * 8];
      accH = __builtin_amdgcn_mfma_f32_16x16x32_bf16(aW, bA[kk], accH, 0, 0, 0);
    }
  }
  // C. hid epilogue (bias+relu -> bf16 LDS)
  {
    int eb = w * 16 + quad * 4;
    float4 b4 = *(const float4*)&fv_b1[eb];
    float v0 = fmaxf(accH[0] + b4.x, 0.0f);
    float v1 = fmaxf(accH[1] + b4.y, 0.0f);
    float v2 = fmaxf(accH[2] + b4.z, 0.0f);
    float v3 = fmaxf(accH[3] + b4.w, 0.0f);
    *(u32*)&hidb[cl * 136 + eb] = pack2(v0, v1);
    *(u32*)&hidb[cl * 136 + eb + 2] = pack2(v2, v3);
  }
  __syncthreads();
  // D. x2 = hid @ fv_w2 + b2 + h; write x2out; x2 -> bf16 LDS
  {
    short8 bH2[4];
#pragma unroll
    for (int kk = 0; kk < 4; kk++)
      bH2[kk] = *(const short8*)&hidb[cl * 136 + kk * 32 + quad * 8];
    int gr = r0 + cl;
    f32x4 acc2 = zero;
#pragma unroll
    for (int kk = 0; kk < 4; kk++) {
      short8 aW = *(const short8*)&g_w2t[(w * 16 + cl) * 128 + kk * 32 + quad * 8];
      acc2 = __builtin_amdgcn_mfma_f32_16x16x32_bf16(aW, bH2[kk], acc2, 0, 0, 0);
    }
    int eb = w * 16 + quad * 4;
    float4 b4 = *(const float4*)&fv_b2[eb];
    float4 h4 = *(const float4*)&g_h[gr * 128 + eb];
    float4 xv;
    xv.x = acc2[0] + b4.x + h4.x;
    xv.y = acc2[1] + b4.y + h4.y;
    xv.z = acc2[2] + b4.z + h4.z;
    xv.w = acc2[3] + b4.w + h4.w;
    *(float4*)&x2out[gr * 128 + eb] = xv;
    *(u32*)&x2b[cl * 136 + eb] = pack2(xv.x, xv.y);
    *(u32*)&x2b[cl * 136 + eb + 2] = pack2(xv.z, xv.w);
  }
  __syncthreads();
  // E/F. A = x2 @ feA + fe_b1 ; B = x2 @ feB
  {
    short8 bX[4];
#pragma unroll
    for (int kk = 0; kk < 4; kk++)
      bX[kk] = *(const short8*)&x2b[cl * 136 + kk * 32 + quad * 8];
    int gr = r0 + cl;
    f32x4 accA = zero, accB = zero;
#pragma unroll
    for (int kk = 0; kk < 4; kk++) {
      short8 aWA = *(const short8*)&g_fat[(w * 16 + cl) * 128 + kk * 32 + quad * 8];
      short8 aWB = *(const short8*)&g_fat[16384 + (w * 16 + cl) * 128 + kk * 32 + quad * 8];
      accA = __builtin_amdgcn_mfma_f32_16x16x32_bf16(aWA, bX[kk], accA, 0, 0, 0);
      accB = __builtin_amdgcn_mfma_f32_16x16x32_bf16(aWB, bX[kk], accB, 0, 0, 0);
    }
    int eb = w * 16 + quad * 4;
    float4 b4 = *(const float4*)&fe_b1[eb];
    float4 av;
    av.x = accA[0] + b4.x; av.y = accA[1] + b4.y;
    av.z = accA[2] + b4.z; av.w = accA[3] + b4.w;
    *(float4*)&g_A[gr * 128 + eb] = av;
    *(f32x4*)&g_Bm[gr * 128 + eb] = accB;
  }
}

// ---------------- Kernel 4: pairwise edge FFN (A_i + B_j factorized) -------------
__global__ void k_edge(const float* __restrict__ few2, const float* __restrict__ feb2,
                       float* __restrict__ edge) {
  __shared__ float As[4 * 128];
  __shared__ float w2s[128];
  int b = blockIdx.x, tx = threadIdx.x;
  int n = b >> 8, rest = b & 255, ig = rest >> 1, jh = rest & 1;
  int i0 = ig * 4;
  if (tx < 128) w2s[tx] = few2[tx];
  As[tx] = g_A[(n * 512 + i0) * 128 + tx];
  As[tx + 256] = g_A[(n * 512 + i0) * 128 + tx + 256];
  float eb2 = feb2[0];
  __syncthreads();
  int j = jh * 256 + tx;
  const float* B0 = &g_Bm[(n * 512 + j) * 128];
  float acc[4] = {};
#pragma unroll 4
  for (int dc = 0; dc < 32; dc++) {
    float4 bv = *(const float4*)&B0[dc * 4];
    float4 w4 = *(const float4*)&w2s[dc * 4];
#pragma unroll
    for (int i = 0; i < 4; i++) {
      float4 a4 = *(const float4*)&As[i * 128 + dc * 4];
      acc[i] = fmaf(fmaxf(a4.x + bv.x, 0.0f), w4.x, acc[i]);
      acc[i] = fmaf(fmaxf(a4.y + bv.y, 0.0f), w4.y, acc[i]);
      acc[i] = fmaf(fmaxf(a4.z + bv.z, 0.0f), w4.z, acc[i]);
      acc[i] = fmaf(fmaxf(a4.w + bv.w, 0.0f), w4.w, acc[i]);
    }
  }
  const float scale = 1.0f / 512.0f;
#pragma unroll
  for (int i = 0; i < 4; i++)
    edge[(n * 512 + i0 + i) * 512 + j] = (acc[i] + eb2) * scale;
}

extern "C" void kernel_launch(void* const* d_in, const int* in_sizes, int n_in,
                              void* d_out, int out_size, void* d_ws, size_t ws_size,
                              hipStream_t stream) {
  (void)in_sizes; (void)n_in; (void)out_size; (void)d_ws; (void)ws_size;
  const float* x     = (const float*)d_in[0];
  const float* fn_w1 = (const float*)d_in[1];
  const float* fn_b1 = (const float*)d_in[2];
  const float* fn_w2 = (const float*)d_in[3];
  const float* fn_b2 = (const float*)d_in[4];
  const float* wk    = (const float*)d_in[5];
  const float* bk    = (const float*)d_in[6];
  const float* wq    = (const float*)d_in[7];
  const float* bq    = (const float*)d_in[8];
  const float* wv    = (const float*)d_in[9];
  const float* bv    = (const float*)d_in[10];
  const float* fv_w1 = (const float*)d_in[11];
  const float* fv_b1 = (const float*)d_in[12];
  const float* fv_w2 = (const float*)d_in[13];
  const float* fv_b2 = (const float*)d_in[14];
  const float* fe_w1 = (const float*)d_in[15];
  const float* fe_b1 = (const float*)d_in[16];
  const float* fe_w2 = (const float*)d_in[17];
  const float* fe_b2 = (const float*)d_in[18];

  float* x2out = (float*)d_out;      // [0, 131072) floats
  float* edge  = x2out + 131072;     // [131072, 655360) floats

  k_fnode<<<512, 256, 0, stream>>>(x, fn_w1, fn_b1, fn_w2, fn_b2, wk, wq, wv,
                                   fv_w1, fv_w2, fe_w1);
  k_qattn<<<512, 256, 0, stream>>>(bk, bq, bv);
  k_fv<<<64, 512, 0, stream>>>(fv_b1, fv_b2, fe_b1, x2out);
  k_edge<<<512, 256, 0, stream>>>(fe_w2, fe_b2, edge);
}

// Round 6
// 148.314 us; speedup vs baseline: 2.3798x; 1.2112x over previous
//
#include <hip/hip_runtime.h>

typedef unsigned short u16;
typedef unsigned int u32;
typedef __attribute__((ext_vector_type(8))) short short8;
typedef __attribute__((ext_vector_type(4))) float f32x4;

__device__ __forceinline__ u16 f2b(float f) {
  union { float f; u32 i; } v; v.f = f;
  u32 i = v.i;
  return (u16)((i + 0x7FFFu + ((i >> 16) & 1u)) >> 16);
}
__device__ __forceinline__ float lo16(u32 x) { union { u32 i; float f; } v; v.i = x << 16; return v.f; }
__device__ __forceinline__ float hi16(u32 x) { union { u32 i; float f; } v; v.i = x & 0xffff0000u; return v.f; }
__device__ __forceinline__ u32 pack2(float a, float b) { return (u32)f2b(a) | ((u32)f2b(b) << 16); }

// Sizes: N=2, M=512, D_IN=64, D=128, H=8. Rows = N*M = 1024. hn = h*2+n in [0,16).
__device__ __align__(16) float g_h[1024 * 128];
__device__ __align__(16) u16   g_hb[1024 * 128];
__device__ __align__(16) u16   g_Wt[24 * 128 * 128];   // W^T per (proj,head): [ph][e][d] bf16
__device__ __align__(16) u16   g_w1t[128 * 1024];      // fv_w1^T: [e][k] bf16
__device__ __align__(16) u16   g_w2t[128 * 128];       // fv_w2^T: [e][k] bf16
__device__ __align__(16) u16   g_fat[2 * 128 * 128];   // fe_w1^T halves: [half][e][k] bf16
__device__ __align__(16) u16   g_Opb[512 * 64 * 128];  // bf16 flash partials
__device__ __align__(16) float g_ml[512 * 64 * 2];
__device__ __align__(16) float g_A[1024 * 128];
__device__ __align__(16) float g_Bm[1024 * 128];

// ---------------- Kernel 1: f_node (+ weight pre-transpose piggyback) ------------
__global__ void k_fnode(const float* __restrict__ x, const float* __restrict__ w1,
                        const float* __restrict__ b1, const float* __restrict__ w2,
                        const float* __restrict__ b2, const float* __restrict__ wk,
                        const float* __restrict__ wq, const float* __restrict__ wv,
                        const float* __restrict__ fvw1, const float* __restrict__ fvw2,
                        const float* __restrict__ few1) {
  __shared__ float xr[2 * 64];
  __shared__ float hids[2 * 256];
  __shared__ float red[2048];
  int tx = threadIdx.x;
  int row0 = blockIdx.x * 2;
  if (tx < 128) {
    int r = tx >> 6, k = tx & 63;
    xr[tx] = x[(row0 + r) * 64 + k] + sinf((float)k * (5.0f / 63.0f));
  }
  // piggyback: transpose all MFMA-consumed weights to bf16
  {
    int base = blockIdx.x * 1280 + tx;
#pragma unroll
    for (int t = 0; t < 5; t++) {
      int idx = base + t * 256;
      if (idx < 393216) {
        int ph = idx >> 14, rem = idx & 16383, e = rem >> 7, d = rem & 127;
        int proj = ph >> 3, head = ph & 7;
        const float* W = (proj == 0) ? wk : (proj == 1) ? wq : wv;
        g_Wt[idx] = f2b(W[head * 16384 + d * 128 + e]);
      } else if (idx < 524288) {
        int idx2 = idx - 393216;          // fv_w1^T
        int e = idx2 >> 10, k = idx2 & 1023;
        g_w1t[idx2] = f2b(fvw1[k * 128 + e]);
      } else if (idx < 540672) {
        int idx3 = idx - 524288;          // fv_w2^T
        int e = idx3 >> 7, k = idx3 & 127;
        g_w2t[idx3] = f2b(fvw2[k * 128 + e]);
      } else if (idx < 573440) {
        int idx4 = idx - 540672;          // fe_w1^T halves
        int half = idx4 >> 14, rem = idx4 & 16383;
        int e = rem >> 7, k = rem & 127;
        g_fat[idx4] = f2b(few1[(half * 128 + k) * 128 + e]);
      }
    }
  }
  __syncthreads();
  {
    int ks = tx >> 6, cg = tx & 63;
    float acc[2][4] = {};
#pragma unroll 4
    for (int i = 0; i < 16; i++) {
      int k = ks * 16 + i;
      float4 w4 = *(const float4*)&w1[k * 256 + cg * 4];
      float a0 = xr[k], a1 = xr[64 + k];
      acc[0][0] = fmaf(a0, w4.x, acc[0][0]); acc[0][1] = fmaf(a0, w4.y, acc[0][1]);
      acc[0][2] = fmaf(a0, w4.z, acc[0][2]); acc[0][3] = fmaf(a0, w4.w, acc[0][3]);
      acc[1][0] = fmaf(a1, w4.x, acc[1][0]); acc[1][1] = fmaf(a1, w4.y, acc[1][1]);
      acc[1][2] = fmaf(a1, w4.z, acc[1][2]); acc[1][3] = fmaf(a1, w4.w, acc[1][3]);
    }
#pragma unroll
    for (int r = 0; r < 2; r++)
      *(float4*)&red[ks * 512 + r * 256 + cg * 4] = *(float4*)acc[r];
  }
  __syncthreads();
#pragma unroll
  for (int jo = 0; jo < 2; jo++) {
    int o = jo * 256 + tx;
    float s = red[o] + red[512 + o] + red[1024 + o] + red[1536 + o];
    hids[o] = fmaxf(s + b1[o & 255], 0.0f);
  }
  __syncthreads();
  {
    int ks = tx >> 5, eg = tx & 31;
    float acc[2][4] = {};
#pragma unroll 4
    for (int i = 0; i < 32; i++) {
      int k = ks * 32 + i;
      float4 w4 = *(const float4*)&w2[k * 128 + eg * 4];
      float a0 = hids[k], a1 = hids[256 + k];
      acc[0][0] = fmaf(a0, w4.x, acc[0][0]); acc[0][1] = fmaf(a0, w4.y, acc[0][1]);
      acc[0][2] = fmaf(a0, w4.z, acc[0][2]); acc[0][3] = fmaf(a0, w4.w, acc[0][3]);
      acc[1][0] = fmaf(a1, w4.x, acc[1][0]); acc[1][1] = fmaf(a1, w4.y, acc[1][1]);
      acc[1][2] = fmaf(a1, w4.z, acc[1][2]); acc[1][3] = fmaf(a1, w4.w, acc[1][3]);
    }
    __syncthreads();
#pragma unroll
    for (int r = 0; r < 2; r++)
      *(float4*)&red[ks * 256 + r * 128 + eg * 4] = *(float4*)acc[r];
  }
  __syncthreads();
  {
    float s = 0.0f;
#pragma unroll
    for (int ks = 0; ks < 8; ks++) s += red[ks * 256 + tx];
    int r = tx >> 7, e = tx & 127;
    float v = s + b2[e];
    g_h[(row0 + r) * 128 + e] = v;
    g_hb[(row0 + r) * 128 + e] = f2b(v);
  }
}

// ---------------- Kernel 2: fused K/Q/V projection + flash attention -------------
// Same fusion as R5 but with LDS-STAGED weight tiles (L2-direct MFMA operands
// measured 3-5x slower). RW region triple-serves: W-stage -> Ks -> Pw+alphas.
__global__ __launch_bounds__(256) void k_qattn(
    const float* __restrict__ bk, const float* __restrict__ bq,
    const float* __restrict__ bv) {
  __shared__ u16 RW[128 * 136];   // 34,816 B: W stage / Ks / Pw+alphas
  __shared__ u16 Qs[64 * 136];    // 17,408 B
  __shared__ u16 Vt[128 * 72];    // 18,432 B   (total 70,656 B -> 2 blk/CU)
  u16* Ks = RW;                   // 64*136 (aliases RW after WtK consumed)
  u16* Pw = RW;                   // 64*72   (aliases RW after WtV consumed)
  float* alphas = (float*)&RW[16384];  // byte 32768, clear of Pw (9216 B)

  int b = blockIdx.x, tx = threadIdx.x;
  int jc = b & 3, it = (b >> 2) & 7, hn = b >> 5;
  int head = hn >> 1, n = hn & 1;
  int i0 = it * 64;
  int lane = tx & 63, wv = tx >> 6, cl = lane & 15, quad = lane >> 4;
  const u16* WtK = g_Wt + head * 16384;
  const u16* WtQ = g_Wt + (8 + head) * 16384;
  const u16* WtV = g_Wt + (16 + head) * 16384;
  f32x4 zero = {0.0f, 0.0f, 0.0f, 0.0f};

  // ---- stage WtK (coalesced) ----
#pragma unroll
  for (int t = 0; t < 8; t++) {
    int idx = t * 256 + tx, row = idx >> 4, oct = idx & 15;
    *(uint4*)&RW[row * 136 + oct * 8] = *(const uint4*)&WtK[row * 128 + oct * 8];
  }
  __syncthreads();
  // ---- K projection: rows i0..i0+63 -> Ks ----
  {
    const u16* hbK = &g_hb[(n * 512 + i0 + wv * 16 + cl) * 128];
    short8 bH[4];
#pragma unroll
    for (int kk = 0; kk < 4; kk++)
      bH[kk] = *(const short8*)&hbK[kk * 32 + quad * 8];
    f32x4 acc[8];
#pragma unroll
    for (int em = 0; em < 8; em++) acc[em] = zero;
#pragma unroll
    for (int em = 0; em < 8; em++)
#pragma unroll
      for (int kk = 0; kk < 4; kk++) {
        short8 aW = *(const short8*)&RW[(em * 16 + cl) * 136 + kk * 32 + quad * 8];
        acc[em] = __builtin_amdgcn_mfma_f32_16x16x32_bf16(aW, bH[kk], acc[em], 0, 0, 0);
      }
    __syncthreads();   // all RW (WtK) ds_reads done -> safe to overwrite with Ks
#pragma unroll
    for (int em = 0; em < 8; em++) {
      float4 b4 = *(const float4*)&bk[head * 128 + em * 16 + quad * 4];
      int addr = (wv * 16 + cl) * 136 + em * 16 + quad * 4;
      *(u32*)&Ks[addr] = pack2(acc[em][0] + b4.x, acc[em][1] + b4.y);
      *(u32*)&Ks[addr + 2] = pack2(acc[em][2] + b4.z, acc[em][3] + b4.w);
    }
  }
  __syncthreads();
  // hoist K fragments to registers; RW region then reusable
  short8 bK[4];
#pragma unroll
  for (int kk = 0; kk < 4; kk++)
    bK[kk] = *(const short8*)&Ks[(wv * 16 + cl) * 136 + kk * 32 + quad * 8];

  f32x4 o[8];
#pragma unroll
  for (int es = 0; es < 8; es++) o[es] = zero;
  float m_ = -1e30f, l_ = 0.0f;

  for (int jt = 0; jt < 2; jt++) {
    int j0 = jc * 128 + jt * 64;
    __syncthreads();   // bK hoist done (jt0) / prior PV ds_reads done (jt1)
    // h fragments for rows j0.. (shared by Q and V projections)
    const u16* hbJ = &g_hb[(n * 512 + j0 + wv * 16 + cl) * 128];
    short8 bH[4];
#pragma unroll
    for (int kk = 0; kk < 4; kk++)
      bH[kk] = *(const short8*)&hbJ[kk * 32 + quad * 8];
    // ---- stage WtQ; Q projection -> Qs ----
#pragma unroll
    for (int t = 0; t < 8; t++) {
      int idx = t * 256 + tx, row = idx >> 4, oct = idx & 15;
      *(uint4*)&RW[row * 136 + oct * 8] = *(const uint4*)&WtQ[row * 128 + oct * 8];
    }
    __syncthreads();
    {
      f32x4 acc[8];
#pragma unroll
      for (int em = 0; em < 8; em++) acc[em] = zero;
#pragma unroll
      for (int em = 0; em < 8; em++)
#pragma unroll
        for (int kk = 0; kk < 4; kk++) {
          short8 aW = *(const short8*)&RW[(em * 16 + cl) * 136 + kk * 32 + quad * 8];
          acc[em] = __builtin_amdgcn_mfma_f32_16x16x32_bf16(aW, bH[kk], acc[em], 0, 0, 0);
        }
#pragma unroll
      for (int em = 0; em < 8; em++) {
        float4 b4 = *(const float4*)&bq[head * 128 + em * 16 + quad * 4];
        int addr = (wv * 16 + cl) * 136 + em * 16 + quad * 4;
        *(u32*)&Qs[addr] = pack2(acc[em][0] + b4.x, acc[em][1] + b4.y);
        *(u32*)&Qs[addr + 2] = pack2(acc[em][2] + b4.z, acc[em][3] + b4.w);
      }
    }
    __syncthreads();   // RW (WtQ) reads done -> restage
    // ---- stage WtV; V projection -> Vt (transposed [e][jlocal]) ----
#pragma unroll
    for (int t = 0; t < 8; t++) {
      int idx = t * 256 + tx, row = idx >> 4, oct = idx & 15;
      *(uint4*)&RW[row * 136 + oct * 8] = *(const uint4*)&WtV[row * 128 + oct * 8];
    }
    __syncthreads();
    {
      f32x4 acc[8];
#pragma unroll
      for (int em = 0; em < 8; em++) acc[em] = zero;
#pragma unroll
      for (int em = 0; em < 8; em++)
#pragma unroll
        for (int kk = 0; kk < 4; kk++) {
          short8 aW = *(const short8*)&RW[(em * 16 + cl) * 136 + kk * 32 + quad * 8];
          acc[em] = __builtin_amdgcn_mfma_f32_16x16x32_bf16(aW, bH[kk], acc[em], 0, 0, 0);
        }
      int jl = wv * 16 + cl;
#pragma unroll
      for (int em = 0; em < 8; em++) {
        float4 b4 = *(const float4*)&bv[head * 128 + em * 16 + quad * 4];
        Vt[(em * 16 + quad * 4 + 0) * 72 + jl] = f2b(acc[em][0] + b4.x);
        Vt[(em * 16 + quad * 4 + 1) * 72 + jl] = f2b(acc[em][1] + b4.y);
        Vt[(em * 16 + quad * 4 + 2) * 72 + jl] = f2b(acc[em][2] + b4.z);
        Vt[(em * 16 + quad * 4 + 3) * 72 + jl] = f2b(acc[em][3] + b4.w);
      }
    }
    __syncthreads();   // RW (WtV) reads done; Qs/Vt visible to all
    // ---- QK^T, online softmax, PV (verified) ----
    f32x4 st[4];
#pragma unroll
    for (int s = 0; s < 4; s++) {
      f32x4 acc = zero;
#pragma unroll
      for (int kk = 0; kk < 4; kk++) {
        short8 aQ = *(const short8*)&Qs[(s * 16 + cl) * 136 + kk * 32 + quad * 8];
        acc = __builtin_amdgcn_mfma_f32_16x16x32_bf16(aQ, bK[kk], acc, 0, 0, 0);
      }
      st[s] = acc;
    }
    float p[4][4];
    float tm = -1e30f;
#pragma unroll
    for (int s = 0; s < 4; s++)
#pragma unroll
      for (int r = 0; r < 4; r++) {
        float v = st[s][r];
        v = fmaxf(v, 0.2f * v);
        p[s][r] = v;
        tm = fmaxf(tm, v);
      }
    tm = fmaxf(tm, __shfl_xor(tm, 16));
    tm = fmaxf(tm, __shfl_xor(tm, 32));
    float mn = fmaxf(m_, tm);
    float alpha = __expf(m_ - mn);
    m_ = mn;
    float ps = 0.0f;
#pragma unroll
    for (int s = 0; s < 4; s++)
#pragma unroll
      for (int r = 0; r < 4; r++) {
        float e = __expf(p[s][r] - mn);
        p[s][r] = e;
        ps += e;
      }
    ps += __shfl_xor(ps, 16);
    ps += __shfl_xor(ps, 32);
    l_ = l_ * alpha + ps;
#pragma unroll
    for (int s = 0; s < 4; s++) {
      uint2 w2v = make_uint2(pack2(p[s][0], p[s][1]), pack2(p[s][2], p[s][3]));
      *(uint2*)&Pw[(wv * 16 + cl) * 72 + s * 16 + quad * 4] = w2v;
    }
    if (quad == 0) alphas[wv * 16 + cl] = alpha;
    __syncthreads();
    f32x4 av = *(const f32x4*)&alphas[wv * 16 + quad * 4];
#pragma unroll
    for (int es = 0; es < 8; es++) o[es] *= av;
    short8 aP[2];
#pragma unroll
    for (int k2 = 0; k2 < 2; k2++)
      aP[k2] = *(const short8*)&Pw[(wv * 16 + cl) * 72 + k2 * 32 + quad * 8];
#pragma unroll
    for (int es = 0; es < 8; es++) {
#pragma unroll
      for (int k2 = 0; k2 < 2; k2++) {
        short8 bV = *(const short8*)&Vt[(es * 16 + cl) * 72 + k2 * 32 + quad * 8];
        o[es] = __builtin_amdgcn_mfma_f32_16x16x32_bf16(aP[k2], bV, o[es], 0, 0, 0);
      }
    }
  }
#pragma unroll
  for (int es = 0; es < 8; es++)
#pragma unroll
    for (int r = 0; r < 4; r++)
      g_Opb[(b * 64 + wv * 16 + quad * 4 + r) * 128 + es * 16 + cl] = f2b(o[es][r]);
  if (quad == 0) {
    g_ml[(b * 64 + wv * 16 + cl) * 2 + 0] = m_;
    g_ml[(b * 64 + wv * 16 + cl) * 2 + 1] = l_;
  }
}

// ---------------- Kernel 3: merge + fv MLP + residual + A/B (512 thr, staged) ---
__global__ __launch_bounds__(512) void k_fv(
    const float* __restrict__ fv_b1, const float* __restrict__ fv_b2,
    const float* __restrict__ fe_b1, float* __restrict__ x2out) {
  __shared__ u16 atts[16 * 1032];   // row stride 1032 (pad 8)
  __shared__ u16 wst[128 * 136];    // staged weight tile (reused 11x)
  __shared__ u16 hidb[16 * 136];
  __shared__ u16 x2b[16 * 136];
  int b = blockIdx.x, tx = threadIdx.x;
  int r0 = b * 16;

  // A. merge 4 flash partials -> atts (normalized + leaky, bf16)
  {
    int task = tx >> 2, q4 = tx & 3;             // 128 tasks x 4 e-quarters
    int lr = task >> 3, head = task & 7;
    int gr = r0 + lr;
    int n = gr >> 9, i = gr & 511;
    int it = i >> 6, lr64 = i & 63;
    int hn = head * 2 + n;
    int mlbase = (hn * 32 + it * 4) * 64 + lr64;
    float mc[4], lc[4];
#pragma unroll
    for (int c = 0; c < 4; c++) {
      float2 ml = *(const float2*)&g_ml[(mlbase + c * 64) * 2];
      mc[c] = ml.x; lc[c] = ml.y;
    }
    float ms = fmaxf(fmaxf(mc[0], mc[1]), fmaxf(mc[2], mc[3]));
    float lsum = 0.0f;
    float ra[32];
#pragma unroll
    for (int i2 = 0; i2 < 32; i2++) ra[i2] = 0.0f;
#pragma unroll
    for (int c = 0; c < 4; c++) {
      float w = __expf(mc[c] - ms);
      lsum += w * lc[c];
      const u16* src = &g_Opb[(mlbase + c * 64) * 128 + q4 * 32];
#pragma unroll
      for (int ov = 0; ov < 4; ov++) {
        uint4 v = *(const uint4*)&src[ov * 8];
        ra[ov * 8 + 0] = fmaf(w, lo16(v.x), ra[ov * 8 + 0]);
        ra[ov * 8 + 1] = fmaf(w, hi16(v.x), ra[ov * 8 + 1]);
        ra[ov * 8 + 2] = fmaf(w, lo16(v.y), ra[ov * 8 + 2]);
        ra[ov * 8 + 3] = fmaf(w, hi16(v.y), ra[ov * 8 + 3]);
        ra[ov * 8 + 4] = fmaf(w, lo16(v.z), ra[ov * 8 + 4]);
        ra[ov * 8 + 5] = fmaf(w, hi16(v.z), ra[ov * 8 + 5]);
        ra[ov * 8 + 6] = fmaf(w, lo16(v.w), ra[ov * 8 + 6]);
        ra[ov * 8 + 7] = fmaf(w, hi16(v.w), ra[ov * 8 + 7]);
      }
    }
    float inv = 1.0f / lsum;
    u32 pk[16];
#pragma unroll
    for (int i2 = 0; i2 < 16; i2++) {
      float v0 = ra[i2 * 2] * inv;     v0 = fmaxf(v0, 0.2f * v0);
      float v1 = ra[i2 * 2 + 1] * inv; v1 = fmaxf(v1, 0.2f * v1);
      pk[i2] = pack2(v0, v1);
    }
    int dst = lr * 1032 + head * 128 + q4 * 32;
#pragma unroll
    for (int ov = 0; ov < 4; ov++)
      *(uint4*)&atts[dst + ov * 8] =
          make_uint4(pk[ov * 4], pk[ov * 4 + 1], pk[ov * 4 + 2], pk[ov * 4 + 3]);
  }
  __syncthreads();

  int lane = tx & 63, w = tx >> 6, cl = lane & 15, quad = lane >> 4;
  f32x4 zero = {0.0f, 0.0f, 0.0f, 0.0f};

  // B. hid = atts @ fv_w1 (K=1024, staged per kc); wave w owns em = w
  f32x4 accH = zero;
  for (int kc = 0; kc < 8; kc++) {
#pragma unroll
    for (int t = 0; t < 4; t++) {
      int idx = t * 512 + tx, row = idx >> 4, oct = idx & 15;
      *(uint4*)&wst[row * 136 + oct * 8] =
          *(const uint4*)&g_w1t[row * 1024 + kc * 128 + oct * 8];
    }
    __syncthreads();
    short8 bA[4];
#pragma unroll
    for (int kk = 0; kk < 4; kk++)
      bA[kk] = *(const short8*)&atts[cl * 1032 + kc * 128 + kk * 32 + quad * 8];
#pragma unroll
    for (int kk = 0; kk < 4; kk++) {
      short8 aW = *(const short8*)&wst[(w * 16 + cl) * 136 + kk * 32 + quad * 8];
      accH = __builtin_amdgcn_mfma_f32_16x16x32_bf16(aW, bA[kk], accH, 0, 0, 0);
    }
    __syncthreads();
  }
  // C. hid epilogue (bias+relu -> bf16 LDS)
  {
    int eb = w * 16 + quad * 4;
    float4 b4 = *(const float4*)&fv_b1[eb];
    float v0 = fmaxf(accH[0] + b4.x, 0.0f);
    float v1 = fmaxf(accH[1] + b4.y, 0.0f);
    float v2 = fmaxf(accH[2] + b4.z, 0.0f);
    float v3 = fmaxf(accH[3] + b4.w, 0.0f);
    *(u32*)&hidb[cl * 136 + eb] = pack2(v0, v1);
    *(u32*)&hidb[cl * 136 + eb + 2] = pack2(v2, v3);
  }
  // stage fv_w2^T
#pragma unroll
  for (int t = 0; t < 4; t++) {
    int idx = t * 512 + tx, row = idx >> 4, oct = idx & 15;
    *(uint4*)&wst[row * 136 + oct * 8] = *(const uint4*)&g_w2t[row * 128 + oct * 8];
  }
  __syncthreads();
  // D. x2 = hid @ fv_w2 + b2 + h; write x2out; x2 -> bf16 LDS
  {
    short8 bH2[4];
#pragma unroll
    for (int kk = 0; kk < 4; kk++)
      bH2[kk] = *(const short8*)&hidb[cl * 136 + kk * 32 + quad * 8];
    int gr = r0 + cl;
    f32x4 acc2 = zero;
#pragma unroll
    for (int kk = 0; kk < 4; kk++) {
      short8 aW = *(const short8*)&wst[(w * 16 + cl) * 136 + kk * 32 + quad * 8];
      acc2 = __builtin_amdgcn_mfma_f32_16x16x32_bf16(aW, bH2[kk], acc2, 0, 0, 0);
    }
    int eb = w * 16 + quad * 4;
    float4 b4 = *(const float4*)&fv_b2[eb];
    float4 h4 = *(const float4*)&g_h[gr * 128 + eb];
    float4 xv;
    xv.x = acc2[0] + b4.x + h4.x;
    xv.y = acc2[1] + b4.y + h4.y;
    xv.z = acc2[2] + b4.z + h4.z;
    xv.w = acc2[3] + b4.w + h4.w;
    *(float4*)&x2out[gr * 128 + eb] = xv;
    *(u32*)&x2b[cl * 136 + eb] = pack2(xv.x, xv.y);
    *(u32*)&x2b[cl * 136 + eb + 2] = pack2(xv.z, xv.w);
  }
  __syncthreads();   // wst reads done; x2b visible
  // E. A = x2 @ feA + fe_b1 (staged)
#pragma unroll
  for (int t = 0; t < 4; t++) {
    int idx = t * 512 + tx, row = idx >> 4, oct = idx & 15;
    *(uint4*)&wst[row * 136 + oct * 8] = *(const uint4*)&g_fat[row * 128 + oct * 8];
  }
  __syncthreads();
  short8 bX[4];
#pragma unroll
  for (int kk = 0; kk < 4; kk++)
    bX[kk] = *(const short8*)&x2b[cl * 136 + kk * 32 + quad * 8];
  {
    int gr = r0 + cl;
    f32x4 accA = zero;
#pragma unroll
    for (int kk = 0; kk < 4; kk++) {
      short8 aW = *(const short8*)&wst[(w * 16 + cl) * 136 + kk * 32 + quad * 8];
      accA = __builtin_amdgcn_mfma_f32_16x16x32_bf16(aW, bX[kk], accA, 0, 0, 0);
    }
    int eb = w * 16 + quad * 4;
    float4 b4 = *(const float4*)&fe_b1[eb];
    float4 av;
    av.x = accA[0] + b4.x; av.y = accA[1] + b4.y;
    av.z = accA[2] + b4.z; av.w = accA[3] + b4.w;
    *(float4*)&g_A[gr * 128 + eb] = av;
  }
  __syncthreads();
  // F. B = x2 @ feB (staged)
#pragma unroll
  for (int t = 0; t < 4; t++) {
    int idx = t * 512 + tx, row = idx >> 4, oct = idx & 15;
    *(uint4*)&wst[row * 136 + oct * 8] =
        *(const uint4*)&g_fat[16384 + row * 128 + oct * 8];
  }
  __syncthreads();
  {
    int gr = r0 + cl;
    f32x4 accB = zero;
#pragma unroll
    for (int kk = 0; kk < 4; kk++) {
      short8 aW = *(const short8*)&wst[(w * 16 + cl) * 136 + kk * 32 + quad * 8];
      accB = __builtin_amdgcn_mfma_f32_16x16x32_bf16(aW, bX[kk], accB, 0, 0, 0);
    }
    int eb = w * 16 + quad * 4;
    *(f32x4*)&g_Bm[gr * 128 + eb] = accB;
  }
}

// ---------------- Kernel 4: pairwise edge FFN (A_i + B_j factorized) -------------
__global__ void k_edge(const float* __restrict__ few2, const float* __restrict__ feb2,
                       float* __restrict__ edge) {
  __shared__ float As[4 * 128];
  __shared__ float w2s[128];
  int b = blockIdx.x, tx = threadIdx.x;
  int n = b >> 8, rest = b & 255, ig = rest >> 1, jh = rest & 1;
  int i0 = ig * 4;
  if (tx < 128) w2s[tx] = few2[tx];
  As[tx] = g_A[(n * 512 + i0) * 128 + tx];
  As[tx + 256] = g_A[(n * 512 + i0) * 128 + tx + 256];
  float eb2 = feb2[0];
  __syncthreads();
  int j = jh * 256 + tx;
  const float* B0 = &g_Bm[(n * 512 + j) * 128];
  float acc[4] = {};
#pragma unroll 4
  for (int dc = 0; dc < 32; dc++) {
    float4 bv = *(const float4*)&B0[dc * 4];
    float4 w4 = *(const float4*)&w2s[dc * 4];
#pragma unroll
    for (int i = 0; i < 4; i++) {
      float4 a4 = *(const float4*)&As[i * 128 + dc * 4];
      acc[i] = fmaf(fmaxf(a4.x + bv.x, 0.0f), w4.x, acc[i]);
      acc[i] = fmaf(fmaxf(a4.y + bv.y, 0.0f), w4.y, acc[i]);
      acc[i] = fmaf(fmaxf(a4.z + bv.z, 0.0f), w4.z, acc[i]);
      acc[i] = fmaf(fmaxf(a4.w + bv.w, 0.0f), w4.w, acc[i]);
    }
  }
  const float scale = 1.0f / 512.0f;
#pragma unroll
  for (int i = 0; i < 4; i++)
    edge[(n * 512 + i0 + i) * 512 + j] = (acc[i] + eb2) * scale;
}

extern "C" void kernel_launch(void* const* d_in, const int* in_sizes, int n_in,
                              void* d_out, int out_size, void* d_ws, size_t ws_size,
                              hipStream_t stream) {
  (void)in_sizes; (void)n_in; (void)out_size; (void)d_ws; (void)ws_size;
  const float* x     = (const float*)d_in[0];
  const float* fn_w1 = (const float*)d_in[1];
  const float* fn_b1 = (const float*)d_in[2];
  const float* fn_w2 = (const float*)d_in[3];
  const float* fn_b2 = (const float*)d_in[4];
  const float* wk    = (const float*)d_in[5];
  const float* bk    = (const float*)d_in[6];
  const float* wq    = (const float*)d_in[7];
  const float* bq    = (const float*)d_in[8];
  const float* wv    = (const float*)d_in[9];
  const float* bv    = (const float*)d_in[10];
  const float* fv_w1 = (const float*)d_in[11];
  const float* fv_b1 = (const float*)d_in[12];
  const float* fv_w2 = (const float*)d_in[13];
  const float* fv_b2 = (const float*)d_in[14];
  const float* fe_w1 = (const float*)d_in[15];
  const float* fe_b1 = (const float*)d_in[16];
  const float* fe_w2 = (const float*)d_in[17];
  const float* fe_b2 = (const float*)d_in[18];

  float* x2out = (float*)d_out;      // [0, 131072) floats
  float* edge  = x2out + 131072;     // [131072, 655360) floats

  k_fnode<<<512, 256, 0, stream>>>(x, fn_w1, fn_b1, fn_w2, fn_b2, wk, wq, wv,
                                   fv_w1, fv_w2, fe_w1);
  k_qattn<<<512, 256, 0, stream>>>(bk, bq, bv);
  k_fv<<<64, 512, 0, stream>>>(fv_b1, fv_b2, fe_b1, x2out);
  k_edge<<<512, 256, 0, stream>>>(fe_w2, fe_b2, edge);
}